// Round 7
// baseline (79.284 us; speedup 1.0000x reference)
//
#include <hip/hip_runtime.h>
#include <stdint.h>

#define G 96
#define GS (G*G)            // 9216
#define ST 104              // LDS row stride in bf16 elems (rows 16B-aligned, 8-bank walk)
#define ARR (G*ST)          // 9984 elems = 19968 B per array
#define NT 128              // 2 waves; 1 sample per WG; 4 WG/CU

typedef short bf16x8  __attribute__((ext_vector_type(8)));
typedef float f32x4   __attribute__((ext_vector_type(4)));
typedef uint32_t u32x2 __attribute__((ext_vector_type(2)));

__device__ __forceinline__ short f2bf(float f) {
  uint32_t u = __builtin_bit_cast(uint32_t, f);
  u += 0x7FFFu + ((u >> 16) & 1u);          // RNE
  return (short)(u >> 16);
}
__device__ __forceinline__ uint32_t pk2(float a, float b) {   // 2 bf16 in a dword
  return (uint32_t)(uint16_t)f2bf(a) | ((uint32_t)(uint16_t)f2bf(b) << 16);
}
__device__ __forceinline__ float unlo(uint32_t u) {
  return __builtin_bit_cast(float, u << 16);
}
__device__ __forceinline__ float unhi(uint32_t u) {
  return __builtin_bit_cast(float, u & 0xffff0000u);
}

// acc[i][j][r] = (P * Q^T)[wm + i*16 + (lane>>4)*4 + r][j*16 + (lane&15)]
// wave strip: 3 row-tiles (48 rows), 6 col-tiles (96 cols): 9 reads -> 18 MFMA per ks.
__device__ __forceinline__ void mm_v7(const short* __restrict__ P,
                                      const short* __restrict__ Q,
                                      int wm, int lr, int lq,
                                      f32x4 acc[3][6]) {
  #pragma unroll
  for (int ks = 0; ks < 3; ++ks) {
    const int k0 = ks*32 + lq*8;
    bf16x8 af[3], bg[6];
    #pragma unroll
    for (int i = 0; i < 3; ++i)
      af[i] = *reinterpret_cast<const bf16x8*>(&P[(wm + i*16 + lr)*ST + k0]);
    #pragma unroll
    for (int j = 0; j < 6; ++j)
      bg[j] = *reinterpret_cast<const bf16x8*>(&Q[(j*16 + lr)*ST + k0]);
    #pragma unroll
    for (int i = 0; i < 3; ++i)
      #pragma unroll
      for (int j = 0; j < 6; ++j)
        acc[i][j] = __builtin_amdgcn_mfma_f32_16x16x32_bf16(af[i], bg[j], acc[i][j], 0, 0, 0);
  }
}

#define ZERO18(A) do { \
  _Pragma("unroll") for (int i_=0;i_<3;i_++) \
    _Pragma("unroll") for (int j_=0;j_<6;j_++) A[i_][j_] = (f32x4){0.f,0.f,0.f,0.f}; \
} while (0)

// 4-pass, all-register traces: A=x^2, A^T, B3=x^3, B3^T.
// t0=tr(A), t1=tr(B3), t2=<A,A^T>, t3=<A^T,B3>, t4=<B3,B3^T> (all elementwise regs).
// Dead accumulators packed to bf16 pairs (72->36 regs) to stay under the 256-reg cap.
__global__ __launch_bounds__(NT, 2) void acoef_kernel(
    const float* __restrict__ x, const float* __restrict__ coef,
    float* __restrict__ out) {
  __shared__ short sm[2*ARR];     // X | R1(x^T -> A^T), 39936 B -> 4 WG/CU
  __shared__ float red[2][8];
  __shared__ float cf[20];

  short* X  = sm;
  short* R1 = sm + ARR;

  const int tid  = threadIdx.x;
  const int b    = blockIdx.x;
  const int lane = tid & 63;
  const int w    = tid >> 6;
  const int wm   = w * 48;          // wave row base
  const int lr   = lane & 15;
  const int lq   = lane >> 4;
  const int cr0  = lq * 4;

  if (tid < 20) cf[tid] = coef[tid];

  // ---- stage x: 2 float4 global -> 1 b128 LDS write per iter ----
  const float* xg = x + (size_t)b * GS;
  #pragma unroll
  for (int it = 0; it < 9; ++it) {
    int c = tid + it*NT;                    // b128 chunk 0..1151
    float4 v0 = reinterpret_cast<const float4*>(xg)[2*c];
    float4 v1 = reinterpret_cast<const float4*>(xg)[2*c+1];
    int row = c / 12, col8 = (c - row*12) * 8;
    bf16x8 sv = { f2bf(v0.x), f2bf(v0.y), f2bf(v0.z), f2bf(v0.w),
                  f2bf(v1.x), f2bf(v1.y), f2bf(v1.z), f2bf(v1.w) };
    *reinterpret_cast<bf16x8*>(&X[row*ST + col8]) = sv;
  }
  __syncthreads();                                    // B1

  // ---- build x^T by read-back (reads contiguous-free; writes ~4-way) ----
  #pragma unroll
  for (int it = 0; it < 18; ++it) {
    int u  = tid + it*NT;                   // 0..2303
    int r2 = u % 96, cb = (u / 96) * 4;
    uint32_t p0 = pk2(0.f, 0.f), p1 = p0;   // placeholder init (overwritten)
    short s0 = X[(cb+0)*ST + r2], s1 = X[(cb+1)*ST + r2];
    short s2 = X[(cb+2)*ST + r2], s3 = X[(cb+3)*ST + r2];
    p0 = (uint32_t)(uint16_t)s0 | ((uint32_t)(uint16_t)s1 << 16);
    p1 = (uint32_t)(uint16_t)s2 | ((uint32_t)(uint16_t)s3 << 16);
    u32x2 pv = {p0, p1};
    *reinterpret_cast<u32x2*>(&R1[r2*ST + cb]) = pv;  // xT[r2][cb..+3]
  }
  __syncthreads();                                    // B2

  // ---- pass A: accA = x * x = A ----
  f32x4 acc[3][6];
  ZERO18(acc);
  mm_v7(X, R1, wm, lr, lq, acc);

  float t0 = 0.f;
  uint32_t pkA[3][6][2];                    // A as bf16 pairs (rows r0r1, r2r3)
  #pragma unroll
  for (int i = 0; i < 3; ++i)
    #pragma unroll
    for (int j = 0; j < 6; ++j) {
      const int row0 = wm + i*16 + cr0, col = j*16 + lr;
      #pragma unroll
      for (int r = 0; r < 4; ++r)
        if (row0 + r == col) t0 += acc[i][j][r];
      pkA[i][j][0] = pk2(acc[i][j][0], acc[i][j][1]);
      pkA[i][j][1] = pk2(acc[i][j][2], acc[i][j][3]);
    }                                       // accA dies

  // ---- pass AT: acc = x^T * x^T = A^T ----
  ZERO18(acc);
  mm_v7(R1, X, wm, lr, lq, acc);

  // t2 = tr(x^4) = <A, A^T> elementwise
  float t2 = 0.f;
  uint32_t pkAT[3][6][2];
  #pragma unroll
  for (int i = 0; i < 3; ++i)
    #pragma unroll
    for (int j = 0; j < 6; ++j) {
      t2 += unlo(pkA[i][j][0]) * acc[i][j][0] + unhi(pkA[i][j][0]) * acc[i][j][1]
          + unlo(pkA[i][j][1]) * acc[i][j][2] + unhi(pkA[i][j][1]) * acc[i][j][3];
      pkAT[i][j][0] = pk2(acc[i][j][0], acc[i][j][1]);
      pkAT[i][j][1] = pk2(acc[i][j][2], acc[i][j][3]);
    }                                       // accAT dies (kept as pkAT)
  __syncthreads();                                    // B3 (all x^T reads done)

  // ---- store A^T row-major into R1 from pkA: contiguous b64 ----
  #pragma unroll
  for (int i = 0; i < 3; ++i)
    #pragma unroll
    for (int j = 0; j < 6; ++j) {
      const int row0 = wm + i*16 + cr0, col = j*16 + lr;
      u32x2 pv = {pkA[i][j][0], pkA[i][j][1]};
      *reinterpret_cast<u32x2*>(&R1[col*ST + row0]) = pv;  // A^T[col][row0..+3]
    }                                       // pkA dies
  __syncthreads();                                    // B4 (A^T ready)

  // ---- pass B: acc = x * A = x^3 = B3 ----
  ZERO18(acc);
  mm_v7(X, R1, wm, lr, lq, acc);

  // t1 = tr(x^3); t3 = tr(x^5) = <A^T, B3> elementwise
  float t1 = 0.f, t3 = 0.f;
  uint32_t pkB[3][6][2];
  #pragma unroll
  for (int i = 0; i < 3; ++i)
    #pragma unroll
    for (int j = 0; j < 6; ++j) {
      const int row0 = wm + i*16 + cr0, col = j*16 + lr;
      #pragma unroll
      for (int r = 0; r < 4; ++r)
        if (row0 + r == col) t1 += acc[i][j][r];
      t3 += unlo(pkAT[i][j][0]) * acc[i][j][0] + unhi(pkAT[i][j][0]) * acc[i][j][1]
          + unlo(pkAT[i][j][1]) * acc[i][j][2] + unhi(pkAT[i][j][1]) * acc[i][j][3];
      pkB[i][j][0] = pk2(acc[i][j][0], acc[i][j][1]);
      pkB[i][j][1] = pk2(acc[i][j][2], acc[i][j][3]);
    }                                       // accB3, pkAT die

  // ---- pass BT: acc = A^T * x^T = (x^3)^T ----
  ZERO18(acc);
  mm_v7(R1, X, wm, lr, lq, acc);

  // t4 = tr(x^6) = <B3, B3^T> elementwise
  float t4 = 0.f;
  #pragma unroll
  for (int i = 0; i < 3; ++i)
    #pragma unroll
    for (int j = 0; j < 6; ++j)
      t4 += unlo(pkB[i][j][0]) * acc[i][j][0] + unhi(pkB[i][j][0]) * acc[i][j][1]
          + unlo(pkB[i][j][1]) * acc[i][j][2] + unhi(pkB[i][j][1]) * acc[i][j][3];

  // ---- reduce 5 partials: per-wave shfl, then 2-entry LDS combine ----
  #pragma unroll
  for (int off = 32; off > 0; off >>= 1) {
    t0 += __shfl_down(t0, off, 64);
    t1 += __shfl_down(t1, off, 64);
    t2 += __shfl_down(t2, off, 64);
    t3 += __shfl_down(t3, off, 64);
    t4 += __shfl_down(t4, off, 64);
  }
  if (lane == 0) {
    red[w][0]=t0; red[w][1]=t1; red[w][2]=t2; red[w][3]=t3; red[w][4]=t4;
  }
  __syncthreads();                                    // B5
  if (tid == 0) {
    float T[5];
    #pragma unroll
    for (int k = 0; k < 5; ++k) T[k] = red[0][k] + red[1][k];
    const float inv = 1.0f / (float)GS;
    float o = 0.f, pi = 1.f;
    #pragma unroll
    for (int i = 0; i < 5; ++i) {
      float u = T[i] * inv;
      float up = u;
      #pragma unroll
      for (int j = 0; j < 4; ++j) { o += cf[i*4+j] * up * pi; up *= u; }
      pi *= inv;
    }
    out[b] = o;
  }
}

extern "C" void kernel_launch(void* const* d_in, const int* in_sizes, int n_in,
                              void* d_out, int out_size, void* d_ws, size_t ws_size,
                              hipStream_t stream) {
  const float* x    = (const float*)d_in[0];
  const float* coef = (const float*)d_in[1];
  float* out        = (float*)d_out;
  const int batch   = in_sizes[0] / GS;
  acoef_kernel<<<batch, NT, 0, stream>>>(x, coef, out);
}

// Round 8
// 33.746 us; speedup vs baseline: 2.3494x; 2.3494x over previous
//
#include <hip/hip_runtime.h>
#include <stdint.h>

#define G 96
#define GS (G*G)            // 9216
#define ST 104              // LDS row stride in bf16 elems (16B-aligned rows)
#define ARR (G*ST)          // 9984 elems = 19968 B per array
#define NT 256

typedef short bf16x8  __attribute__((ext_vector_type(8)));
typedef short short4v __attribute__((ext_vector_type(4)));
typedef float f32x4   __attribute__((ext_vector_type(4)));

__device__ __forceinline__ short f2bf(float f) {
  uint32_t u = __builtin_bit_cast(uint32_t, f);
  u += 0x7FFFu + ((u >> 16) & 1u);          // RNE
  return (short)(u >> 16);
}
__device__ __forceinline__ float bf2f(short s) {
  uint32_t u = ((uint32_t)(uint16_t)s) << 16;
  return __builtin_bit_cast(float, u);
}
__device__ __forceinline__ float unlo(uint32_t u) {
  return __builtin_bit_cast(float, u << 16);
}
__device__ __forceinline__ float unhi(uint32_t u) {
  return __builtin_bit_cast(float, u & 0xffff0000u);
}

// Proven fragment convention: af from P rows, bg from Q rows ->
// acc[i][j][r] = (P * Q^T)[wm + i*16 + (lane>>4)*4 + r][wn + j*16 + (lane&15)]
__device__ __forceinline__ void mm_phase(const short* __restrict__ P,
                                         const short* __restrict__ Q,
                                         int wm, int wn, int lr, int lq,
                                         f32x4 acc[3][3]) {
  #pragma unroll
  for (int ks = 0; ks < 3; ++ks) {
    const int k0 = ks*32 + lq*8;
    bf16x8 af[3], bg[3];
    #pragma unroll
    for (int i = 0; i < 3; ++i)
      af[i] = *reinterpret_cast<const bf16x8*>(&P[(wm + i*16 + lr)*ST + k0]);
    #pragma unroll
    for (int j = 0; j < 3; ++j)
      bg[j] = *reinterpret_cast<const bf16x8*>(&Q[(wn + j*16 + lr)*ST + k0]);
    #pragma unroll
    for (int i = 0; i < 3; ++i)
      #pragma unroll
      for (int j = 0; j < 3; ++j)
        acc[i][j] = __builtin_amdgcn_mfma_f32_16x16x32_bf16(af[i], bg[j], acc[i][j], 0, 0, 0);
  }
}

#define ZERO9(A) do { \
  _Pragma("unroll") for (int i_=0;i_<3;i_++) \
    _Pragma("unroll") for (int j_=0;j_<3;j_++) A[i_][j_] = (f32x4){0.f,0.f,0.f,0.f}; \
} while (0)

// 3-pass, shared-partner traces. A=x^2, B3=x^3, X4=x^4 (X never overwritten).
//   t0=tr(A)               diag(acc1)
//   t1=tr(x^3)=Σ A∘x^T_rm  conflict-free scalar reads of R1 (x^T) pre-overwrite
//   pr = A^T_rm[row0+r][col] (conflict-free, packed bf16, read ONCE) serves:
//   t2=tr(x^4)=Σ A ∘pr, t3=tr(x^5)=Σ B3∘pr, t4=tr(x^6)=Σ x^4∘pr
__global__ __launch_bounds__(NT, 3) void acoef_kernel(
    const float* __restrict__ x, const float* __restrict__ coef,
    float* __restrict__ out) {
  __shared__ short sm[2*ARR];     // X | R1(x^T -> A^T -> B3^T), 39936 B -> 4 WG/CU
  __shared__ float red[4][8];
  __shared__ float cf[20];

  short* X  = sm;
  short* R1 = sm + ARR;

  const int tid  = threadIdx.x;
  const int b    = blockIdx.x;
  const int lane = tid & 63;
  const int w    = tid >> 6;
  const int wm   = (w >> 1) * 48;
  const int wn   = (w & 1)  * 48;
  const int lr   = lane & 15;
  const int lq   = lane >> 4;
  const int cr0  = lq * 4;

  if (tid < 20) cf[tid] = coef[tid];

  // ---- stage x bf16 row-major: 2 float4 global -> 1 b128 LDS write ----
  const float* xg = x + (size_t)b * GS;
  #pragma unroll
  for (int it = 0; it < 5; ++it) {
    int c = tid + it*NT;                    // b128 chunk 0..1151
    if (c < GS/8) {
      float4 v0 = reinterpret_cast<const float4*>(xg)[2*c];
      float4 v1 = reinterpret_cast<const float4*>(xg)[2*c+1];
      int row = c / 12, col8 = (c - row*12) * 8;
      bf16x8 sv = { f2bf(v0.x), f2bf(v0.y), f2bf(v0.z), f2bf(v0.w),
                    f2bf(v1.x), f2bf(v1.y), f2bf(v1.z), f2bf(v1.w) };
      *reinterpret_cast<bf16x8*>(&X[row*ST + col8]) = sv;
    }
  }
  __syncthreads();                                    // B1

  // ---- build x^T by read-back (reads conflict-free; b64 writes ~2-way) ----
  #pragma unroll
  for (int it = 0; it < 9; ++it) {
    int u  = tid + it*NT;                   // 0..2303
    int r2 = u % 96, cb = (u / 96) * 4;
    short4v sv = { X[(cb+0)*ST + r2], X[(cb+1)*ST + r2],
                   X[(cb+2)*ST + r2], X[(cb+3)*ST + r2] };
    *reinterpret_cast<short4v*>(&R1[r2*ST + cb]) = sv;   // xT[r2][cb..+3]
  }
  __syncthreads();                                    // B2

  // ---- pass 1: acc1 = x * x = A ----
  f32x4 acc1[3][3];
  ZERO9(acc1);
  mm_phase(X, R1, wm, wn, lr, lq, acc1);

  // t0 = tr(A); t1 = tr(x^3) = Σ A[row][col] * x^T_rm[row][col] (conflict-free)
  float t0 = 0.f, t1 = 0.f;
  #pragma unroll
  for (int i = 0; i < 3; ++i)
    #pragma unroll
    for (int j = 0; j < 3; ++j) {
      const int row0 = wm + i*16 + cr0, col = wn + j*16 + lr;
      #pragma unroll
      for (int r = 0; r < 4; ++r) {
        float a = acc1[i][j][r];
        if (row0 + r == col) t0 += a;
        t1 += a * bf2f(R1[(row0+r)*ST + col]);   // x[col][row0+r]
      }
    }
  __syncthreads();                                    // B3 (x^T dead)

  // ---- store A^T row-major into R1: contiguous b64 ----
  #pragma unroll
  for (int i = 0; i < 3; ++i)
    #pragma unroll
    for (int j = 0; j < 3; ++j) {
      const int row0 = wm + i*16 + cr0, col = wn + j*16 + lr;
      short4v sv = {f2bf(acc1[i][j][0]), f2bf(acc1[i][j][1]),
                    f2bf(acc1[i][j][2]), f2bf(acc1[i][j][3])};
      *reinterpret_cast<short4v*>(&R1[col*ST + row0]) = sv;  // A^T[col][row0..+3]
    }
  __syncthreads();                                    // B4 (A^T ready)

  // ---- pass 2: acc2 = x * A = x^3 = B3 ----
  f32x4 acc2[3][3];
  ZERO9(acc2);
  mm_phase(X, R1, wm, wn, lr, lq, acc2);

  // pr = A^T_rm[row0+r][col] = A[col][row0+r], read once (conflict-free),
  // packed to bf16 pairs. t2 = Σ A∘pr; t3 = Σ B3∘pr.
  float t2 = 0.f, t3 = 0.f;
  uint32_t pr[3][3][2];
  #pragma unroll
  for (int i = 0; i < 3; ++i)
    #pragma unroll
    for (int j = 0; j < 3; ++j) {
      const int row0 = wm + i*16 + cr0, col = wn + j*16 + lr;
      uint16_t p0 = (uint16_t)R1[(row0+0)*ST + col];
      uint16_t p1 = (uint16_t)R1[(row0+1)*ST + col];
      uint16_t p2 = (uint16_t)R1[(row0+2)*ST + col];
      uint16_t p3 = (uint16_t)R1[(row0+3)*ST + col];
      uint32_t q0 = (uint32_t)p0 | ((uint32_t)p1 << 16);
      uint32_t q1 = (uint32_t)p2 | ((uint32_t)p3 << 16);
      pr[i][j][0] = q0; pr[i][j][1] = q1;
      t2 += acc1[i][j][0]*unlo(q0) + acc1[i][j][1]*unhi(q0)
          + acc1[i][j][2]*unlo(q1) + acc1[i][j][3]*unhi(q1);
      t3 += acc2[i][j][0]*unlo(q0) + acc2[i][j][1]*unhi(q0)
          + acc2[i][j][2]*unlo(q1) + acc2[i][j][3]*unhi(q1);
    }                                       // acc1 dies
  __syncthreads();                                    // B5 (A^T reads done)

  // ---- store B3^T row-major into R1: contiguous b64 ----
  #pragma unroll
  for (int i = 0; i < 3; ++i)
    #pragma unroll
    for (int j = 0; j < 3; ++j) {
      const int row0 = wm + i*16 + cr0, col = wn + j*16 + lr;
      short4v sv = {f2bf(acc2[i][j][0]), f2bf(acc2[i][j][1]),
                    f2bf(acc2[i][j][2]), f2bf(acc2[i][j][3])};
      *reinterpret_cast<short4v*>(&R1[col*ST + row0]) = sv;  // B3^T[col][row0..+3]
    }                                       // acc2 dies
  __syncthreads();                                    // B6 (B3^T ready)

  // ---- pass 3: acc3 = x * B3 = x^4 ----
  f32x4 acc3[3][3];
  ZERO9(acc3);
  mm_phase(X, R1, wm, wn, lr, lq, acc3);

  // t4 = tr(x^6) = Σ x^4[row][col] * A[col][row] = Σ acc3 ∘ pr (pure regs)
  float t4 = 0.f;
  #pragma unroll
  for (int i = 0; i < 3; ++i)
    #pragma unroll
    for (int j = 0; j < 3; ++j) {
      uint32_t q0 = pr[i][j][0], q1 = pr[i][j][1];
      t4 += acc3[i][j][0]*unlo(q0) + acc3[i][j][1]*unhi(q0)
          + acc3[i][j][2]*unlo(q1) + acc3[i][j][3]*unhi(q1);
    }

  // ---- reduce 5 partials across the workgroup ----
  #pragma unroll
  for (int off = 32; off > 0; off >>= 1) {
    t0 += __shfl_down(t0, off, 64);
    t1 += __shfl_down(t1, off, 64);
    t2 += __shfl_down(t2, off, 64);
    t3 += __shfl_down(t3, off, 64);
    t4 += __shfl_down(t4, off, 64);
  }
  if (lane == 0) {
    red[w][0]=t0; red[w][1]=t1; red[w][2]=t2; red[w][3]=t3; red[w][4]=t4;
  }
  __syncthreads();                                    // B7
  if (tid == 0) {
    float T[5];
    #pragma unroll
    for (int k = 0; k < 5; ++k) T[k] = red[0][k]+red[1][k]+red[2][k]+red[3][k];
    const float inv = 1.0f / (float)GS;
    float o = 0.f, pi = 1.f;
    #pragma unroll
    for (int i = 0; i < 5; ++i) {
      float u = T[i] * inv;
      float up = u;
      #pragma unroll
      for (int j = 0; j < 4; ++j) { o += cf[i*4+j] * up * pi; up *= u; }
      pi *= inv;
    }
    out[b] = o;
  }
}

extern "C" void kernel_launch(void* const* d_in, const int* in_sizes, int n_in,
                              void* d_out, int out_size, void* d_ws, size_t ws_size,
                              hipStream_t stream) {
  const float* x    = (const float*)d_in[0];
  const float* coef = (const float*)d_in[1];
  float* out        = (float*)d_out;
  const int batch   = in_sizes[0] / GS;
  acoef_kernel<<<batch, NT, 0, stream>>>(x, coef, out);
}

// Round 9
// 33.511 us; speedup vs baseline: 2.3659x; 1.0070x over previous
//
#include <hip/hip_runtime.h>
#include <stdint.h>

#define G 96
#define GS (G*G)            // 9216
#define ST 104              // LDS row stride in bf16 elems (16B-aligned rows)
#define ARR (G*ST)          // 9984 elems = 19968 B per array
#define NT 128              // 2 waves per WG, 1 sample per WG, 4 WG/CU

typedef short bf16x8  __attribute__((ext_vector_type(8)));
typedef short short4v __attribute__((ext_vector_type(4)));
typedef float f32x4   __attribute__((ext_vector_type(4)));

__device__ __forceinline__ short f2bf(float f) {
  uint32_t u = __builtin_bit_cast(uint32_t, f);
  u += 0x7FFFu + ((u >> 16) & 1u);          // RNE
  return (short)(u >> 16);
}
__device__ __forceinline__ float bf2f(short s) {
  uint32_t u = ((uint32_t)(uint16_t)s) << 16;
  return __builtin_bit_cast(float, u);
}

// af from P rows, bg from Q rows ->
// acc[i][j][r] = (P * Q^T)[wm + i*16 + (lane>>4)*4 + r][j*16 + (lane&15)]
// 2-wave shape: 3 row-tiles x 6 col-tiles; 9 b128 reads feed 18 MFMA per ks.
__device__ __forceinline__ void mm_phase(const short* __restrict__ P,
                                         const short* __restrict__ Q,
                                         int wm, int lr, int lq,
                                         f32x4 acc[3][6]) {
  #pragma unroll
  for (int ks = 0; ks < 3; ++ks) {
    const int k0 = ks*32 + lq*8;
    bf16x8 af[3], bg[6];
    #pragma unroll
    for (int i = 0; i < 3; ++i)
      af[i] = *reinterpret_cast<const bf16x8*>(&P[(wm + i*16 + lr)*ST + k0]);
    #pragma unroll
    for (int j = 0; j < 6; ++j)
      bg[j] = *reinterpret_cast<const bf16x8*>(&Q[(j*16 + lr)*ST + k0]);
    #pragma unroll
    for (int i = 0; i < 3; ++i)
      #pragma unroll
      for (int j = 0; j < 6; ++j)
        acc[i][j] = __builtin_amdgcn_mfma_f32_16x16x32_bf16(af[i], bg[j], acc[i][j], 0, 0, 0);
  }
}

#define ZERO18(A) do { \
  _Pragma("unroll") for (int i_=0;i_<3;i_++) \
    _Pragma("unroll") for (int j_=0;j_<6;j_++) A[i_][j_] = (f32x4){0.f,0.f,0.f,0.f}; \
} while (0)

// R3 trace scheme verbatim: pass1 A = x*x; pass2 B3^T = A^T * x^T.
// t0=tr(A); t1=diag(B3^T); t2=Σ B3[c][r]·x[r][c] (CF scalar); t3=Σ B3[c][r]·A[r][c]
// (b64 A^T reads); t4=Σ B3[c][r]·B3[r][c] via B3 store + CF scalar re-read.
__global__ __launch_bounds__(NT, 2) void acoef_kernel(
    const float* __restrict__ x, const float* __restrict__ coef,
    float* __restrict__ out) {
  __shared__ short sm[2*ARR];     // X | R1(x^T -> A^T -> B3), 39936 B -> 4 WG/CU
  __shared__ float red[2][8];
  __shared__ float cf[20];

  short* X  = sm;
  short* R1 = sm + ARR;

  const int tid  = threadIdx.x;
  const int b    = blockIdx.x;
  const int lane = tid & 63;
  const int w    = tid >> 6;
  const int wm   = w * 48;          // wave row base (2 waves x 48 rows)
  const int lr   = lane & 15;
  const int lq   = lane >> 4;
  const int cr0  = lq * 4;

  if (tid < 20) cf[tid] = coef[tid];

  // ---- stage x bf16 row-major: 2 float4 global -> 1 b128 LDS write ----
  const float* xg = x + (size_t)b * GS;
  #pragma unroll
  for (int it = 0; it < 9; ++it) {
    int c = tid + it*NT;                    // b128 chunk 0..1151
    float4 v0 = reinterpret_cast<const float4*>(xg)[2*c];
    float4 v1 = reinterpret_cast<const float4*>(xg)[2*c+1];
    int row = c / 12, col8 = (c - row*12) * 8;
    bf16x8 sv = { f2bf(v0.x), f2bf(v0.y), f2bf(v0.z), f2bf(v0.w),
                  f2bf(v1.x), f2bf(v1.y), f2bf(v1.z), f2bf(v1.w) };
    *reinterpret_cast<bf16x8*>(&X[row*ST + col8]) = sv;
  }
  __syncthreads();                                    // B1

  // ---- build x^T by read-back (reads conflict-free; b64 writes ~8-way) ----
  #pragma unroll
  for (int it = 0; it < 18; ++it) {
    int u  = tid + it*NT;                   // 0..2303
    int r2 = u % 96, cb = (u / 96) * 4;
    short4v sv = { X[(cb+0)*ST + r2], X[(cb+1)*ST + r2],
                   X[(cb+2)*ST + r2], X[(cb+3)*ST + r2] };
    *reinterpret_cast<short4v*>(&R1[r2*ST + cb]) = sv;   // xT[r2][cb..+3]
  }
  __syncthreads();                                    // B2

  // ---- pass 1: acc1 = x * x = A;  acc1[i][j][r] = A[row0+r][col] ----
  f32x4 acc1[3][6];
  ZERO18(acc1);
  mm_phase(X, R1, wm, lr, lq, acc1);

  float t0 = 0.f;
  #pragma unroll
  for (int i = 0; i < 3; ++i)
    #pragma unroll
    for (int j = 0; j < 6; ++j) {
      const int row0 = wm + i*16 + cr0, col = j*16 + lr;
      #pragma unroll
      for (int r = 0; r < 4; ++r)
        if (row0 + r == col) t0 += acc1[i][j][r];      // tr(x^2)
    }
  __syncthreads();                                    // B3 (x^T dead)

  // ---- store A^T row-major into R1: contiguous b64; acc1 dies ----
  #pragma unroll
  for (int i = 0; i < 3; ++i)
    #pragma unroll
    for (int j = 0; j < 6; ++j) {
      const int row0 = wm + i*16 + cr0, col = j*16 + lr;
      short4v sv = {f2bf(acc1[i][j][0]), f2bf(acc1[i][j][1]),
                    f2bf(acc1[i][j][2]), f2bf(acc1[i][j][3])};
      *reinterpret_cast<short4v*>(&R1[col*ST + row0]) = sv;  // A^T[col][row0..+3]
    }
  __syncthreads();                                    // B4 (A^T ready)

  // ---- pass 2: acc2 = A^T * x^T = B3^T;  acc2[i][j][r] = B3[col][row0+r] ----
  f32x4 acc2[3][6];
  ZERO18(acc2);
  mm_phase(R1, X, wm, lr, lq, acc2);

  float t1 = 0.f, t2 = 0.f, t3 = 0.f;
  #pragma unroll
  for (int i = 0; i < 3; ++i)
    #pragma unroll
    for (int j = 0; j < 6; ++j) {
      const int row0 = wm + i*16 + cr0, col = j*16 + lr;
      // A[row0+r][col] = A^T[col][row0+r] -> b64 read (8-way)
      short4v ar = *reinterpret_cast<const short4v*>(&R1[col*ST + row0]);
      #pragma unroll
      for (int r = 0; r < 4; ++r) {
        float wv = acc2[i][j][r];                   // B3[col][row0+r]
        if (row0 + r == col) t1 += wv;              // tr(x^3)
        t2 += wv * bf2f(X[(row0+r)*ST + col]);      // tr(x^4): x[row][col], CF
        t3 += wv * bf2f(ar[r]);                     // tr(x^5): A[row][col]
      }
    }
  __syncthreads();                                    // B5 (A^T reads done)

  // ---- store B3 row-major into R1: contiguous b64 ----
  #pragma unroll
  for (int i = 0; i < 3; ++i)
    #pragma unroll
    for (int j = 0; j < 6; ++j) {
      const int row0 = wm + i*16 + cr0, col = j*16 + lr;
      short4v sv = {f2bf(acc2[i][j][0]), f2bf(acc2[i][j][1]),
                    f2bf(acc2[i][j][2]), f2bf(acc2[i][j][3])};
      *reinterpret_cast<short4v*>(&R1[col*ST + row0]) = sv;  // B3[col][row0..+3]
    }
  __syncthreads();                                    // B6 (B3 ready)

  // ---- t4 = tr(x^6): pair own B3[col][row] with B3[row][col] (CF scalar) ----
  float t4 = 0.f;
  #pragma unroll
  for (int i = 0; i < 3; ++i)
    #pragma unroll
    for (int j = 0; j < 6; ++j) {
      const int row0 = wm + i*16 + cr0, col = j*16 + lr;
      #pragma unroll
      for (int r = 0; r < 4; ++r)
        t4 += acc2[i][j][r] * bf2f(R1[(row0+r)*ST + col]);
    }

  // ---- reduce 5 partials: per-wave shfl, then 2-entry combine ----
  #pragma unroll
  for (int off = 32; off > 0; off >>= 1) {
    t0 += __shfl_down(t0, off, 64);
    t1 += __shfl_down(t1, off, 64);
    t2 += __shfl_down(t2, off, 64);
    t3 += __shfl_down(t3, off, 64);
    t4 += __shfl_down(t4, off, 64);
  }
  if (lane == 0) {
    red[w][0]=t0; red[w][1]=t1; red[w][2]=t2; red[w][3]=t3; red[w][4]=t4;
  }
  __syncthreads();                                    // B7
  if (tid == 0) {
    float T[5];
    #pragma unroll
    for (int k = 0; k < 5; ++k) T[k] = red[0][k] + red[1][k];
    const float inv = 1.0f / (float)GS;
    float o = 0.f, pi = 1.f;
    #pragma unroll
    for (int i = 0; i < 5; ++i) {
      float u = T[i] * inv;
      float up = u;
      #pragma unroll
      for (int j = 0; j < 4; ++j) { o += cf[i*4+j] * up * pi; up *= u; }
      pi *= inv;
    }
    out[b] = o;
  }
}

extern "C" void kernel_launch(void* const* d_in, const int* in_sizes, int n_in,
                              void* d_out, int out_size, void* d_ws, size_t ws_size,
                              hipStream_t stream) {
  const float* x    = (const float*)d_in[0];
  const float* coef = (const float*)d_in[1];
  float* out        = (float*)d_out;
  const int batch   = in_sizes[0] / GS;
  acoef_kernel<<<batch, NT, 0, stream>>>(x, coef, out);
}

// Round 10
// 33.407 us; speedup vs baseline: 2.3733x; 1.0031x over previous
//
#include <hip/hip_runtime.h>
#include <stdint.h>

#define G 96
#define GS (G*G)            // 9216
#define ST 104              // LDS row stride in bf16 elems (16B-aligned rows)
#define ARR (G*ST)          // 9984 elems = 19968 B per array
#define NT 256

typedef short bf16x8  __attribute__((ext_vector_type(8)));
typedef short short4v __attribute__((ext_vector_type(4)));
typedef float f32x4   __attribute__((ext_vector_type(4)));

__device__ __forceinline__ short f2bf(float f) {
  uint32_t u = __builtin_bit_cast(uint32_t, f);
  u += 0x7FFFu + ((u >> 16) & 1u);          // RNE
  return (short)(u >> 16);
}
__device__ __forceinline__ float bf2f(short s) {
  uint32_t u = ((uint32_t)(uint16_t)s) << 16;
  return __builtin_bit_cast(float, u);
}

// R1 bank-swizzle: physical col = col ^ ((row>>2)&3)<<3 elems (16/32/48-B XOR).
// Bijective per row; preserves 8B/16B alignment (XOR is a multiple of 8 elems,
// all accesses are b64 (col%4==0) or b128 (col%8==0) or scalar). Spreads the
// Δrow≡20-bank period-8 aliasing of ST=104 across 4 extra bank groups.
__device__ __forceinline__ int rsw(int rho, int kap) {
  return rho * ST + (kap ^ ((((rho) >> 2) & 3) << 3));
}

// Proven fragment convention: af from P rows, bg from Q rows ->
// acc[i][j][r] = (P * Q^T)[wm + i*16 + (lane>>4)*4 + r][wn + j*16 + (lane&15)]
// P = X (unswizzled rows), Q = R1 (swizzled rows).
__device__ __forceinline__ void mm_phase(const short* __restrict__ P,
                                         const short* __restrict__ Q,
                                         int wm, int wn, int lr, int lq,
                                         f32x4 acc[3][3]) {
  #pragma unroll
  for (int ks = 0; ks < 3; ++ks) {
    const int k0 = ks*32 + lq*8;
    bf16x8 af[3], bg[3];
    #pragma unroll
    for (int i = 0; i < 3; ++i)
      af[i] = *reinterpret_cast<const bf16x8*>(&P[(wm + i*16 + lr)*ST + k0]);
    #pragma unroll
    for (int j = 0; j < 3; ++j)
      bg[j] = *reinterpret_cast<const bf16x8*>(&Q[rsw(wn + j*16 + lr, k0)]);
    #pragma unroll
    for (int i = 0; i < 3; ++i)
      #pragma unroll
      for (int j = 0; j < 3; ++j)
        acc[i][j] = __builtin_amdgcn_mfma_f32_16x16x32_bf16(af[i], bg[j], acc[i][j], 0, 0, 0);
  }
}

#define ZERO9(A) do { \
  _Pragma("unroll") for (int i_=0;i_<3;i_++) \
    _Pragma("unroll") for (int j_=0;j_<3;j_++) A[i_][j_] = (f32x4){0.f,0.f,0.f,0.f}; \
} while (0)

// R3 champion structure: pass1 A = x*x; pass2 B3^T = A^T * x^T.
// t0=tr(A); t1=diag(B3^T); t2=Σ B3[c][r]·x[r][c]; t3=Σ B3[c][r]·A[r][c];
// t4=Σ B3[c][r]·B3[r][c] via B3 store + re-read. R1 swizzled, X linear.
__global__ __launch_bounds__(NT, 3) void acoef_kernel(
    const float* __restrict__ x, const float* __restrict__ coef,
    float* __restrict__ out) {
  __shared__ short sm[2*ARR];     // X | R1(x^T -> A^T -> B3), 39936 B -> 4 WG/CU
  __shared__ float red[4][8];
  __shared__ float cf[20];

  short* X  = sm;
  short* R1 = sm + ARR;

  const int tid  = threadIdx.x;
  const int b    = blockIdx.x;
  const int lane = tid & 63;
  const int w    = tid >> 6;
  const int wm   = (w >> 1) * 48;
  const int wn   = (w & 1)  * 48;
  const int lr   = lane & 15;
  const int lq   = lane >> 4;
  const int cr0  = lq * 4;

  if (tid < 20) cf[tid] = coef[tid];

  // ---- stage x bf16 row-major: 2 float4 global -> 1 b128 LDS write ----
  const float* xg = x + (size_t)b * GS;
  #pragma unroll
  for (int it = 0; it < 5; ++it) {
    int c = tid + it*NT;                    // b128 chunk 0..1151
    if (c < GS/8) {
      float4 v0 = reinterpret_cast<const float4*>(xg)[2*c];
      float4 v1 = reinterpret_cast<const float4*>(xg)[2*c+1];
      int row = c / 12, col8 = (c - row*12) * 8;
      bf16x8 sv = { f2bf(v0.x), f2bf(v0.y), f2bf(v0.z), f2bf(v0.w),
                    f2bf(v1.x), f2bf(v1.y), f2bf(v1.z), f2bf(v1.w) };
      *reinterpret_cast<bf16x8*>(&X[row*ST + col8]) = sv;
    }
  }
  __syncthreads();                                    // B1

  // ---- build x^T by read-back (reads CF; b64 writes now swizzle-spread) ----
  #pragma unroll
  for (int it = 0; it < 9; ++it) {
    int u  = tid + it*NT;                   // 0..2303
    int r2 = u % 96, cb = (u / 96) * 4;
    short4v sv = { X[(cb+0)*ST + r2], X[(cb+1)*ST + r2],
                   X[(cb+2)*ST + r2], X[(cb+3)*ST + r2] };
    *reinterpret_cast<short4v*>(&R1[rsw(r2, cb)]) = sv;   // xT[r2][cb..+3]
  }
  __syncthreads();                                    // B2

  // ---- pass 1: acc1 = x * x = A;  acc1[i][j][r] = A[row0+r][col] ----
  f32x4 acc1[3][3];
  ZERO9(acc1);
  mm_phase(X, R1, wm, wn, lr, lq, acc1);

  float t0 = 0.f;
  #pragma unroll
  for (int i = 0; i < 3; ++i)
    #pragma unroll
    for (int j = 0; j < 3; ++j) {
      const int row0 = wm + i*16 + cr0, col = wn + j*16 + lr;
      #pragma unroll
      for (int r = 0; r < 4; ++r)
        if (row0 + r == col) t0 += acc1[i][j][r];      // tr(x^2)
    }
  __syncthreads();                                    // B3 (x^T dead)

  // ---- store A^T row-major into R1: b64, swizzled; acc1 dies after ----
  #pragma unroll
  for (int i = 0; i < 3; ++i)
    #pragma unroll
    for (int j = 0; j < 3; ++j) {
      const int row0 = wm + i*16 + cr0, col = wn + j*16 + lr;
      short4v sv = {f2bf(acc1[i][j][0]), f2bf(acc1[i][j][1]),
                    f2bf(acc1[i][j][2]), f2bf(acc1[i][j][3])};
      *reinterpret_cast<short4v*>(&R1[rsw(col, row0)]) = sv;  // A^T[col][row0..+3]
    }
  __syncthreads();                                    // B4 (A^T ready)

  // ---- pass 2: acc2 = A^T * x^T = B3^T;  acc2[i][j][r] = B3[col][row0+r] ----
  // af must read R1 (swizzled) rows: inline variant of mm_phase with P=R1.
  f32x4 acc2[3][3];
  ZERO9(acc2);
  #pragma unroll
  for (int ks = 0; ks < 3; ++ks) {
    const int k0 = ks*32 + lq*8;
    bf16x8 af[3], bg[3];
    #pragma unroll
    for (int i = 0; i < 3; ++i)
      af[i] = *reinterpret_cast<const bf16x8*>(&R1[rsw(wm + i*16 + lr, k0)]);
    #pragma unroll
    for (int j = 0; j < 3; ++j)
      bg[j] = *reinterpret_cast<const bf16x8*>(&X[(wn + j*16 + lr)*ST + k0]);
    #pragma unroll
    for (int i = 0; i < 3; ++i)
      #pragma unroll
      for (int j = 0; j < 3; ++j)
        acc2[i][j] = __builtin_amdgcn_mfma_f32_16x16x32_bf16(af[i], bg[j], acc2[i][j], 0, 0, 0);
  }

  float t1 = 0.f, t2 = 0.f, t3 = 0.f;
  #pragma unroll
  for (int i = 0; i < 3; ++i)
    #pragma unroll
    for (int j = 0; j < 3; ++j) {
      const int row0 = wm + i*16 + cr0, col = wn + j*16 + lr;
      // A[row0+r][col] = A^T[col][row0+r] -> b64 swizzled read
      short4v ar = *reinterpret_cast<const short4v*>(&R1[rsw(col, row0)]);
      #pragma unroll
      for (int r = 0; r < 4; ++r) {
        float wv = acc2[i][j][r];                   // B3[col][row0+r]
        if (row0 + r == col) t1 += wv;              // tr(x^3)
        t2 += wv * bf2f(X[(row0+r)*ST + col]);      // tr(x^4): x[row][col]
        t3 += wv * bf2f(ar[r]);                     // tr(x^5): A[row][col]
      }
    }
  __syncthreads();                                    // B5 (A^T reads done)

  // ---- store B3 row-major into R1: b64, swizzled ----
  #pragma unroll
  for (int i = 0; i < 3; ++i)
    #pragma unroll
    for (int j = 0; j < 3; ++j) {
      const int row0 = wm + i*16 + cr0, col = wn + j*16 + lr;
      short4v sv = {f2bf(acc2[i][j][0]), f2bf(acc2[i][j][1]),
                    f2bf(acc2[i][j][2]), f2bf(acc2[i][j][3])};
      *reinterpret_cast<short4v*>(&R1[rsw(col, row0)]) = sv;  // B3[col][row0..+3]
    }
  __syncthreads();                                    // B6 (B3 ready)

  // ---- t4 = tr(x^6): pair own B3[col][row] with B3[row][col] (swz scalar) ----
  float t4 = 0.f;
  #pragma unroll
  for (int i = 0; i < 3; ++i)
    #pragma unroll
    for (int j = 0; j < 3; ++j) {
      const int row0 = wm + i*16 + cr0, col = wn + j*16 + lr;
      #pragma unroll
      for (int r = 0; r < 4; ++r)
        t4 += acc2[i][j][r] * bf2f(R1[rsw(row0 + r, col)]);
    }

  // ---- reduce 5 partials across the workgroup ----
  #pragma unroll
  for (int off = 32; off > 0; off >>= 1) {
    t0 += __shfl_down(t0, off, 64);
    t1 += __shfl_down(t1, off, 64);
    t2 += __shfl_down(t2, off, 64);
    t3 += __shfl_down(t3, off, 64);
    t4 += __shfl_down(t4, off, 64);
  }
  if (lane == 0) {
    red[w][0]=t0; red[w][1]=t1; red[w][2]=t2; red[w][3]=t3; red[w][4]=t4;
  }
  __syncthreads();                                    // B7
  if (tid == 0) {
    float T[5];
    #pragma unroll
    for (int k = 0; k < 5; ++k) T[k] = red[0][k]+red[1][k]+red[2][k]+red[3][k];
    const float inv = 1.0f / (float)GS;
    float o = 0.f, pi = 1.f;
    #pragma unroll
    for (int i = 0; i < 5; ++i) {
      float u = T[i] * inv;
      float up = u;
      #pragma unroll
      for (int j = 0; j < 4; ++j) { o += cf[i*4+j] * up * pi; up *= u; }
      pi *= inv;
    }
    out[b] = o;
  }
}

extern "C" void kernel_launch(void* const* d_in, const int* in_sizes, int n_in,
                              void* d_out, int out_size, void* d_ws, size_t ws_size,
                              hipStream_t stream) {
  const float* x    = (const float*)d_in[0];
  const float* coef = (const float*)d_in[1];
  float* out        = (float*)d_out;
  const int batch   = in_sizes[0] / GS;
  acoef_kernel<<<batch, NT, 0, stream>>>(x, coef, out);
}

// Round 11
// 32.858 us; speedup vs baseline: 2.4129x; 1.0167x over previous
//
#include <hip/hip_runtime.h>
#include <stdint.h>

#define G 96
#define GS (G*G)            // 9216
#define ST 104              // LDS row stride in bf16 elems (16B-aligned rows)
#define ARR (G*ST)          // 9984 elems = 19968 B per array
#define NT 256

typedef short bf16x8  __attribute__((ext_vector_type(8)));
typedef short short4v __attribute__((ext_vector_type(4)));
typedef float f32x4   __attribute__((ext_vector_type(4)));

__device__ __forceinline__ short f2bf(float f) {
  uint32_t u = __builtin_bit_cast(uint32_t, f);
  u += 0x7FFFu + ((u >> 16) & 1u);          // RNE
  return (short)(u >> 16);
}
__device__ __forceinline__ float bf2f(short s) {
  uint32_t u = ((uint32_t)(uint16_t)s) << 16;
  return __builtin_bit_cast(float, u);
}

// Proven fragment convention: af from P rows, bg from Q rows ->
// acc[i][j][r] = (P * Q^T)[wm + i*16 + (lane>>4)*4 + r][wn + j*16 + (lane&15)]
__device__ __forceinline__ void mm_phase(const short* __restrict__ P,
                                         const short* __restrict__ Q,
                                         int wm, int wn, int lr, int lq,
                                         f32x4 acc[3][3]) {
  #pragma unroll
  for (int ks = 0; ks < 3; ++ks) {
    const int k0 = ks*32 + lq*8;
    bf16x8 af[3], bg[3];
    #pragma unroll
    for (int i = 0; i < 3; ++i)
      af[i] = *reinterpret_cast<const bf16x8*>(&P[(wm + i*16 + lr)*ST + k0]);
    #pragma unroll
    for (int j = 0; j < 3; ++j)
      bg[j] = *reinterpret_cast<const bf16x8*>(&Q[(wn + j*16 + lr)*ST + k0]);
    #pragma unroll
    for (int i = 0; i < 3; ++i)
      #pragma unroll
      for (int j = 0; j < 3; ++j)
        acc[i][j] = __builtin_amdgcn_mfma_f32_16x16x32_bf16(af[i], bg[j], acc[i][j], 0, 0, 0);
  }
}

#define ZERO9(A) do { \
  _Pragma("unroll") for (int i_=0;i_<3;i_++) \
    _Pragma("unroll") for (int j_=0;j_<3;j_++) A[i_][j_] = (f32x4){0.f,0.f,0.f,0.f}; \
} while (0)

// R3 champion algorithm, 2 samples per WG with phase-merged interleaving.
// Per sample: pass1 A = x*x; pass2 B3^T = A^T * x^T.
// t0=tr(A); t1=diag(B3^T); t2=Σ B3[c][r]·x[r][c]; t3=Σ B3[c][r]·A[r][c];
// t4=Σ B3[c][r]·B3[r][c] via B3 store + CF scalar re-read.
__global__ __launch_bounds__(NT, 2) void acoef_kernel(
    const float* __restrict__ x, const float* __restrict__ coef,
    float* __restrict__ out) {
  __shared__ short sm[4*ARR];     // X0 | R1_0 | X1 | R1_1 : 79872 B -> 2 WG/CU
  __shared__ float red[4][10];
  __shared__ float cf[20];

  short* Xp[2]  = { sm,           sm + 2*ARR };
  short* R1p[2] = { sm + ARR,     sm + 3*ARR };

  const int tid  = threadIdx.x;
  const int b    = blockIdx.x;
  const int lane = tid & 63;
  const int w    = tid >> 6;
  const int wm   = (w >> 1) * 48;
  const int wn   = (w & 1)  * 48;
  const int lr   = lane & 15;
  const int lq   = lane >> 4;
  const int cr0  = lq * 4;

  if (tid < 20) cf[tid] = coef[tid];

  // ---- stage both samples bf16 row-major (coalesced float4 -> b64 LDS) ----
  #pragma unroll
  for (int s = 0; s < 2; ++s) {
    const float* xg = x + (size_t)(2*b + s) * GS;
    short* X = Xp[s];
    #pragma unroll
    for (int it = 0; it < 9; ++it) {
      int f = tid + it*NT;                    // float4 chunk 0..2303
      float4 v = reinterpret_cast<const float4*>(xg)[f];
      int row = f / 24, c4 = (f - row*24) * 4;
      short4v sv = {f2bf(v.x), f2bf(v.y), f2bf(v.z), f2bf(v.w)};
      *reinterpret_cast<short4v*>(&X[row*ST + c4]) = sv;
    }
  }
  __syncthreads();                                    // B1

  // ---- build x^T for both samples (reads CF; b64 writes) ----
  #pragma unroll
  for (int s = 0; s < 2; ++s) {
    short* X = Xp[s]; short* R1 = R1p[s];
    #pragma unroll
    for (int it = 0; it < 9; ++it) {
      int u  = tid + it*NT;                   // 0..2303
      int r2 = u % 96, cb = (u / 96) * 4;
      short4v sv = { X[(cb+0)*ST + r2], X[(cb+1)*ST + r2],
                     X[(cb+2)*ST + r2], X[(cb+3)*ST + r2] };
      *reinterpret_cast<short4v*>(&R1[r2*ST + cb]) = sv;   // xT[r2][cb..+3]
    }
  }
  __syncthreads();                                    // B2

  float tt[2][5];
  #pragma unroll
  for (int s = 0; s < 2; ++s)
    #pragma unroll
    for (int k = 0; k < 5; ++k) tt[s][k] = 0.f;

  // ---- pass 1 (both samples): acc1 = x*x = A; t0 = tr(A) ----
  f32x4 acc1[2][3][3];
  #pragma unroll
  for (int s = 0; s < 2; ++s) {
    ZERO9(acc1[s]);
    mm_phase(Xp[s], R1p[s], wm, wn, lr, lq, acc1[s]);
    #pragma unroll
    for (int i = 0; i < 3; ++i)
      #pragma unroll
      for (int j = 0; j < 3; ++j) {
        const int row0 = wm + i*16 + cr0, col = wn + j*16 + lr;
        #pragma unroll
        for (int r = 0; r < 4; ++r)
          if (row0 + r == col) tt[s][0] += acc1[s][i][j][r];   // tr(x^2)
      }
  }
  __syncthreads();                                    // B3 (x^T dead)

  // ---- store A^T row-major into R1 (both): contiguous b64; acc1 dies ----
  #pragma unroll
  for (int s = 0; s < 2; ++s) {
    short* R1 = R1p[s];
    #pragma unroll
    for (int i = 0; i < 3; ++i)
      #pragma unroll
      for (int j = 0; j < 3; ++j) {
        const int row0 = wm + i*16 + cr0, col = wn + j*16 + lr;
        short4v sv = {f2bf(acc1[s][i][j][0]), f2bf(acc1[s][i][j][1]),
                      f2bf(acc1[s][i][j][2]), f2bf(acc1[s][i][j][3])};
        *reinterpret_cast<short4v*>(&R1[col*ST + row0]) = sv;  // A^T[col][row0..+3]
      }
  }
  __syncthreads();                                    // B4 (A^T ready)

  // ---- pass 2 (both): acc2 = A^T * x^T = B3^T; t1,t2,t3 epilogue ----
  f32x4 acc2[2][3][3];
  #pragma unroll
  for (int s = 0; s < 2; ++s) {
    ZERO9(acc2[s]);
    mm_phase(R1p[s], Xp[s], wm, wn, lr, lq, acc2[s]);
    short* X = Xp[s]; short* R1 = R1p[s];
    #pragma unroll
    for (int i = 0; i < 3; ++i)
      #pragma unroll
      for (int j = 0; j < 3; ++j) {
        const int row0 = wm + i*16 + cr0, col = wn + j*16 + lr;
        short4v ar = *reinterpret_cast<const short4v*>(&R1[col*ST + row0]);
        #pragma unroll
        for (int r = 0; r < 4; ++r) {
          float wv = acc2[s][i][j][r];                 // B3[col][row0+r]
          if (row0 + r == col) tt[s][1] += wv;         // tr(x^3)
          tt[s][2] += wv * bf2f(X[(row0+r)*ST + col]); // tr(x^4)
          tt[s][3] += wv * bf2f(ar[r]);                // tr(x^5)
        }
      }
  }
  __syncthreads();                                    // B5 (A^T reads done)

  // ---- store B3 row-major into R1 (both): contiguous b64 ----
  #pragma unroll
  for (int s = 0; s < 2; ++s) {
    short* R1 = R1p[s];
    #pragma unroll
    for (int i = 0; i < 3; ++i)
      #pragma unroll
      for (int j = 0; j < 3; ++j) {
        const int row0 = wm + i*16 + cr0, col = wn + j*16 + lr;
        short4v sv = {f2bf(acc2[s][i][j][0]), f2bf(acc2[s][i][j][1]),
                      f2bf(acc2[s][i][j][2]), f2bf(acc2[s][i][j][3])};
        *reinterpret_cast<short4v*>(&R1[col*ST + row0]) = sv;  // B3[col][row0..+3]
      }
  }
  __syncthreads();                                    // B6 (B3 ready)

  // ---- t4 = tr(x^6): pair own B3[col][row] with B3[row][col] (CF scalar) ----
  #pragma unroll
  for (int s = 0; s < 2; ++s) {
    short* R1 = R1p[s];
    #pragma unroll
    for (int i = 0; i < 3; ++i)
      #pragma unroll
      for (int j = 0; j < 3; ++j) {
        const int row0 = wm + i*16 + cr0, col = wn + j*16 + lr;
        #pragma unroll
        for (int r = 0; r < 4; ++r)
          tt[s][4] += acc2[s][i][j][r] * bf2f(R1[(row0+r)*ST + col]);
      }
  }

  // ---- reduce 10 partials across the workgroup ----
  #pragma unroll
  for (int off = 32; off > 0; off >>= 1) {
    #pragma unroll
    for (int s = 0; s < 2; ++s)
      #pragma unroll
      for (int k = 0; k < 5; ++k)
        tt[s][k] += __shfl_down(tt[s][k], off, 64);
  }
  if (lane == 0) {
    #pragma unroll
    for (int s = 0; s < 2; ++s)
      #pragma unroll
      for (int k = 0; k < 5; ++k) red[w][s*5+k] = tt[s][k];
  }
  __syncthreads();                                    // B7
  if (tid < 2) {
    const int s = tid;
    float T[5];
    #pragma unroll
    for (int k = 0; k < 5; ++k)
      T[k] = red[0][s*5+k]+red[1][s*5+k]+red[2][s*5+k]+red[3][s*5+k];
    const float inv = 1.0f / (float)GS;
    float o = 0.f, pi = 1.f;
    #pragma unroll
    for (int i = 0; i < 5; ++i) {
      float u = T[i] * inv;
      float up = u;
      #pragma unroll
      for (int j = 0; j < 4; ++j) { o += cf[i*4+j] * up * pi; up *= u; }
      pi *= inv;
    }
    out[2*b + s] = o;
  }
}

extern "C" void kernel_launch(void* const* d_in, const int* in_sizes, int n_in,
                              void* d_out, int out_size, void* d_ws, size_t ws_size,
                              hipStream_t stream) {
  const float* x    = (const float*)d_in[0];
  const float* coef = (const float*)d_in[1];
  float* out        = (float*)d_out;
  const int batch   = in_sizes[0] / GS;
  acoef_kernel<<<batch/2, NT, 0, stream>>>(x, coef, out);
}